// Round 4
// baseline (228.678 us; speedup 1.0000x reference)
//
#include <hip/hip_runtime.h>
#include <hip/hip_bf16.h>

// GAT layer: out = h = x @ W^T  (N=200000 x 128, fp32 in / fp32 out), then
// E=500 edges: out[dst] += 0.1 * leaky_relu(attn, 0.2) * h[src].
//
// K1 (GEMM, no-LDS): MFMA role-swap — A = W rows (features), B = x rows.
//   * W fragments live in registers (2 feature-tiles per wave = 32 VGPRs),
//     loaded once per block, reused across all row-groups. No LDS, no
//     barriers, no bank conflicts.
//   * C layout (col=lane&15=x-row, row=q*4+r=feature) makes each lane hold
//     4 consecutive features of one row -> dwordx4 stores.
//   * grid 3125 blocks x 256 thr, 64 rows/block (4 groups of 16).
// K2 (edges): single kernel; recomputes h_src/h_dst rows in fp32 from x,W
//   (so it never reads `out`), then one atomicAdd per element. Duplicate
//   dst handled by HW atomics; no workspace.

typedef __attribute__((ext_vector_type(8))) short bf16x8;   // 8 bf16 = 4 VGPRs
typedef __attribute__((ext_vector_type(4))) float f32x4;

__device__ __forceinline__ bf16x8 cvt2frag(float4 v0, float4 v1) {
  union { bf16x8 v; __hip_bfloat16 h[8]; } u;
  u.h[0] = __float2bfloat16(v0.x); u.h[1] = __float2bfloat16(v0.y);
  u.h[2] = __float2bfloat16(v0.z); u.h[3] = __float2bfloat16(v0.w);
  u.h[4] = __float2bfloat16(v1.x); u.h[5] = __float2bfloat16(v1.y);
  u.h[6] = __float2bfloat16(v1.z); u.h[7] = __float2bfloat16(v1.w);
  return u.v;
}

#define ROWGROUPS 4   // 16-row groups per block; 64 rows/block

__global__ __launch_bounds__(256, 5) void gat_gemm_kernel(
    const float* __restrict__ x,
    const float* __restrict__ W,
    float* __restrict__ out,
    int N) {
  const int t = threadIdx.x;
  const int wave = t >> 6;
  const int lane = t & 63;
  const int m = lane & 15;     // x-row within 16-group / D col
  const int q = lane >> 4;     // quad 0..3

  // W fragments for this wave's 2 feature-tiles: nt = wave*2 + {0,1}.
  // A[m'=lane&15][k=q*8+j] -> lane reads W[(nt*16+m)*128 + s*32 + q*8 ..+7]
  bf16x8 wf[2][4];
  #pragma unroll
  for (int l = 0; l < 2; ++l) {
    const int nt = wave * 2 + l;
    const float* wp = W + (nt * 16 + m) * 128 + q * 8;
    #pragma unroll
    for (int s = 0; s < 4; ++s) {
      float4 v0 = *reinterpret_cast<const float4*>(wp + s * 32);
      float4 v1 = *reinterpret_cast<const float4*>(wp + s * 32 + 4);
      wf[l][s] = cvt2frag(v0, v1);
    }
  }

  #pragma unroll
  for (int g = 0; g < ROWGROUPS; ++g) {
    const long rowbase = ((long)blockIdx.x * ROWGROUPS + g) * 16;
    const float* xp = x + (rowbase + m) * 128 + q * 8;

    // B[k=s*32+q*8+j][n=m] = x[rowbase+m][k] — same per-lane addressing.
    float4 v[8];
    #pragma unroll
    for (int s = 0; s < 4; ++s) {
      v[2 * s]     = *reinterpret_cast<const float4*>(xp + s * 32);
      v[2 * s + 1] = *reinterpret_cast<const float4*>(xp + s * 32 + 4);
    }
    bf16x8 xf[4];
    #pragma unroll
    for (int s = 0; s < 4; ++s) xf[s] = cvt2frag(v[2 * s], v[2 * s + 1]);

    f32x4 acc0 = (f32x4){0.f, 0.f, 0.f, 0.f};
    f32x4 acc1 = (f32x4){0.f, 0.f, 0.f, 0.f};
    #pragma unroll
    for (int s = 0; s < 4; ++s) {
      acc0 = __builtin_amdgcn_mfma_f32_16x16x32_bf16(wf[0][s], xf[s], acc0, 0, 0, 0);
      acc1 = __builtin_amdgcn_mfma_f32_16x16x32_bf16(wf[1][s], xf[s], acc1, 0, 0, 0);
    }

    // D[feature = q*4+r][xrow = m]: lane holds 4 consecutive features of
    // row rowbase+m at col base nt*16 + q*4 -> one float4 store per tile.
    float* op = out + (rowbase + m) * 128;
    *reinterpret_cast<float4*>(op + (wave * 2 + 0) * 16 + q * 4) =
        *reinterpret_cast<float4*>(&acc0);
    *reinterpret_cast<float4*>(op + (wave * 2 + 1) * 16 + q * 4) =
        *reinterpret_cast<float4*>(&acc1);
  }
}

__device__ __forceinline__ int detect_i64(const int* eidx) {
  int or_odd = 0;
  #pragma unroll
  for (int k = 0; k < 16; ++k) or_odd |= eidx[2 * k + 1];
  return or_odd == 0;   // int64 little-endian: high words all zero
}

// One block (128 threads) per edge. h_src/h_dst recomputed exactly in fp32
// from x,W (never reads `out`), attn via in-head butterfly reduce, then a
// single atomicAdd per element (HW accumulates duplicate dst).
__global__ __launch_bounds__(128) void gat_edge_kernel(
    const float* __restrict__ x,
    const int* __restrict__ eidx,          // [2,E]: int32 or int64 (detected)
    const float* __restrict__ W,
    const float* __restrict__ a,           // [4, 64]
    float* __restrict__ out,
    int E) {
  const int e = blockIdx.x;
  const int c = threadIdx.x;               // output feature 0..127
  const bool is64 = detect_i64(eidx);
  const int src = is64 ? eidx[2 * e] : eidx[e];
  const int dst = is64 ? eidx[2 * (E + e)] : eidx[E + e];

  const float4* xs = reinterpret_cast<const float4*>(x + (long)src * 128);
  const float4* xd = reinterpret_cast<const float4*>(x + (long)dst * 128);
  const float4* wr = reinterpret_cast<const float4*>(W + (long)c * 128);

  float hs = 0.f, hd = 0.f;
  #pragma unroll 8
  for (int k = 0; k < 32; ++k) {
    float4 w = wr[k], s4 = xs[k], d4 = xd[k];
    hs = fmaf(w.x, s4.x, hs); hs = fmaf(w.y, s4.y, hs);
    hs = fmaf(w.z, s4.z, hs); hs = fmaf(w.w, s4.w, hs);
    hd = fmaf(w.x, d4.x, hd); hd = fmaf(w.y, d4.y, hd);
    hd = fmaf(w.z, d4.z, hd); hd = fmaf(w.w, d4.w, hd);
  }

  const int head = c >> 5, d = c & 31;
  float term = a[head * 64 + d] * hs + a[head * 64 + 32 + d] * hd;
  // heads occupy 32-lane halves of each wave; xor<=16 stays in-head
  term += __shfl_xor(term, 16);
  term += __shfl_xor(term, 8);
  term += __shfl_xor(term, 4);
  term += __shfl_xor(term, 2);
  term += __shfl_xor(term, 1);
  const float attn = term >= 0.f ? term : 0.2f * term;   // leaky_relu(0.2)

  atomicAdd(&out[(long)dst * 128 + c], 0.1f * attn * hs);
}

extern "C" void kernel_launch(void* const* d_in, const int* in_sizes, int n_in,
                              void* d_out, int out_size, void* d_ws, size_t ws_size,
                              hipStream_t stream) {
  const float* x  = (const float*)d_in[0];
  const int* eidx = (const int*)d_in[1];
  const float* W  = (const float*)d_in[2];
  const float* a  = (const float*)d_in[3];
  float* out = (float*)d_out;

  const int N = in_sizes[0] / 128;   // 200000
  const int E = in_sizes[1] / 2;     // 500

  const int blocks = (N + 64 * ROWGROUPS - 1) / (64 * ROWGROUPS) * ((64 * ROWGROUPS) / (16 * ROWGROUPS));
  // N = 200000 = 3125 * 64: each block covers ROWGROUPS*16 = 64 rows.
  gat_gemm_kernel<<<N / (16 * ROWGROUPS), 256, 0, stream>>>(x, W, out, N);
  gat_edge_kernel<<<E, 128, 0, stream>>>(x, eidx, W, a, out, E);
  (void)blocks; (void)d_ws; (void)ws_size; (void)out_size; (void)n_in;
}